// Round 1
// baseline (478.341 us; speedup 1.0000x reference)
//
#include <hip/hip_runtime.h>
#include <hip/hip_bf16.h>

using int32x4 = __attribute__((ext_vector_type(4))) int;

#define BM 128
#define BN 128
#define BKQ 64   // K-bytes per staging step (= one mfma_i32_16x16x64_i8 K)

// ---------------------------------------------------------------------------
// async 16B global->LDS (wave-uniform LDS base + lane*16)
__device__ __forceinline__ void load_lds16(const void* g, void* l) {
    __builtin_amdgcn_global_load_lds(
        (const __attribute__((address_space(1))) unsigned int*)g,
        (__attribute__((address_space(3))) unsigned int*)l, 16, 0, 0);
}

// ---------------------------------------------------------------------------
// Kernel 1: quantize activations to signed int8 (xq - a_zp) and per-row sums.
// One block per row of x [M][K]; K = 4096. Must match numpy: round-half-even
// of correctly-rounded fp32 division.
__global__ __launch_bounds__(256) void quant_rows(
    const float* __restrict__ x, const float* __restrict__ act_scale,
    const int* __restrict__ act_zp, char* __restrict__ xs,
    int* __restrict__ rowsum, int K)
{
    __shared__ int wsum[4];
    const int row = blockIdx.x;
    const float s = act_scale[0];
    const int zp = act_zp[0];
    const float4* __restrict__ xr = (const float4*)(x + (size_t)row * K);
    char4* __restrict__ xo = (char4*)(xs + (size_t)row * K);
    const int nv = K >> 2;
    int sum = 0;
    for (int i = threadIdx.x; i < nv; i += 256) {
        float4 v = xr[i];
        int q0 = min(max((int)rintf(v.x / s) + zp, 0), 255) - zp;
        int q1 = min(max((int)rintf(v.y / s) + zp, 0), 255) - zp;
        int q2 = min(max((int)rintf(v.z / s) + zp, 0), 255) - zp;
        int q3 = min(max((int)rintf(v.w / s) + zp, 0), 255) - zp;
        sum += q0 + q1 + q2 + q3;
        char4 c;
        c.x = (char)q0; c.y = (char)q1; c.z = (char)q2; c.w = (char)q3;
        xo[i] = c;
    }
    // wave64 reduce then cross-wave
    for (int off = 32; off > 0; off >>= 1) sum += __shfl_down(sum, off, 64);
    if ((threadIdx.x & 63) == 0) wsum[threadIdx.x >> 6] = sum;
    __syncthreads();
    if (threadIdx.x == 0) rowsum[row] = wsum[0] + wsum[1] + wsum[2] + wsum[3];
}

// ---------------------------------------------------------------------------
// Kernel 2: weight int32 [N][K] -> int8 (w - 128)
__global__ __launch_bounds__(256) void wconv(
    const int4* __restrict__ wq, char4* __restrict__ wsq, long n4)
{
    long i = (long)blockIdx.x * 256 + threadIdx.x;
    if (i >= n4) return;
    int4 v = wq[i];
    char4 c;
    c.x = (char)(v.x - 128); c.y = (char)(v.y - 128);
    c.z = (char)(v.z - 128); c.w = (char)(v.w - 128);
    wsq[i] = c;
}

// ---------------------------------------------------------------------------
// Kernel 3: fold scales:  alpha[n] = a_s*w_s[n];  beta[n] = alpha[n]*(128-w_zp[n])
__global__ __launch_bounds__(256) void mkscales(
    const float* __restrict__ wscale, const int* __restrict__ wzp,
    const float* __restrict__ act_scale, float* __restrict__ alpha,
    float* __restrict__ beta, int N)
{
    int n = blockIdx.x * 256 + threadIdx.x;
    if (n >= N) return;
    float a = act_scale[0] * wscale[n];
    alpha[n] = a;
    beta[n] = a * (float)(128 - wzp[n]);
}

// ---------------------------------------------------------------------------
// Kernel 4: int8 GEMM, m97 structure. A=[M][K] i8, B=[N][K] i8 (B^T form).
// 128x128 tile, BK=64; 4 waves each 64x64 via 4x4 grid of 16x16x64 i8 MFMAs.
// Epilogue: C[m][n] = alpha[n]*dot + beta[n]*rowsum[m] + bias[n]
__global__ __launch_bounds__(256) void gemm_i8(
    const char* __restrict__ Aq, const char* __restrict__ Bq,
    const int* __restrict__ rowsum, const float* __restrict__ alpha,
    const float* __restrict__ beta, const float* __restrict__ bias,
    float* __restrict__ C, int M, int N, int K)
{
    __shared__ __align__(16) char As[BM * BKQ];  // 8 KiB
    __shared__ __align__(16) char Bs[BN * BKQ];  // 8 KiB

    const int tid  = threadIdx.x;
    const int wave = tid >> 6;
    const int lane = tid & 63;

    const int n0 = blockIdx.x * BN;
    const int m0 = blockIdx.y * BM;

    const int wm = (wave & 1) * 64;   // wave's m-offset in tile
    const int wn = (wave >> 1) * 64;  // wave's n-offset in tile

    // staging chunk assignment: chunk c (16B) -> row c>>2, colblk c&3
    const int cA  = wave * 128 + lane;      // u = 0
    const int cA2 = cA + 64;                // u = 1
    const char* aga = Aq + (size_t)(m0 + (cA  >> 2)) * K + (cA  & 3) * 16;
    const char* agb = Aq + (size_t)(m0 + (cA2 >> 2)) * K + (cA2 & 3) * 16;
    const char* bga = Bq + (size_t)(n0 + (cA  >> 2)) * K + (cA  & 3) * 16;
    const char* bgb = Bq + (size_t)(n0 + (cA2 >> 2)) * K + (cA2 & 3) * 16;
    char* lA0 = As + wave * 2048;
    char* lA1 = As + wave * 2048 + 1024;
    char* lB0 = Bs + wave * 2048;
    char* lB1 = Bs + wave * 2048 + 1024;

    int32x4 acc[4][4] = {};

    const int r = lane & 15;       // row within 16-tile (A: m, B: n)
    const int q = lane >> 4;       // k quadrant (16B each)

    for (int k0 = 0; k0 < K; k0 += BKQ) {
        __syncthreads();   // previous iteration's LDS reads done
        load_lds16(aga, lA0); aga += BKQ;
        load_lds16(agb, lA1); agb += BKQ;
        load_lds16(bga, lB0); bga += BKQ;
        load_lds16(bgb, lB1); bgb += BKQ;
        __syncthreads();   // staging drained (compiler inserts vmcnt(0))

        int32x4 af[4], bf[4];
#pragma unroll
        for (int i = 0; i < 4; i++)
            af[i] = *(const int32x4*)(As + (wm + i * 16 + r) * 64 + q * 16);
#pragma unroll
        for (int j = 0; j < 4; j++)
            bf[j] = *(const int32x4*)(Bs + (wn + j * 16 + r) * 64 + q * 16);

#pragma unroll
        for (int i = 0; i < 4; i++)
#pragma unroll
            for (int j = 0; j < 4; j++)
                acc[i][j] = __builtin_amdgcn_mfma_i32_16x16x64_i8(
                    af[i], bf[j], acc[i][j], 0, 0, 0);
    }

    // epilogue: C/D layout col=lane&15, row=(lane>>4)*4+reg  (dtype-independent)
    const int r4  = (lane >> 4) * 4;
    const int cil = lane & 15;
#pragma unroll
    for (int j = 0; j < 4; j++) {
        const int col = n0 + wn + j * 16 + cil;
        const float al = alpha[col];
        const float be = beta[col];
        const float bi = bias[col];
#pragma unroll
        for (int i = 0; i < 4; i++) {
            const int rowb = m0 + wm + i * 16 + r4;
#pragma unroll
            for (int t = 0; t < 4; t++) {
                const int row = rowb + t;
                C[(size_t)row * N + col] =
                    al * (float)acc[i][j][t] + be * (float)rowsum[row] + bi;
            }
        }
    }
}

// ---------------------------------------------------------------------------
extern "C" void kernel_launch(void* const* d_in, const int* in_sizes, int n_in,
                              void* d_out, int out_size, void* d_ws, size_t ws_size,
                              hipStream_t stream) {
    const float* x      = (const float*)d_in[0];
    const int*   wq     = (const int*)d_in[1];
    const float* wscale = (const float*)d_in[2];
    const int*   wzp    = (const int*)d_in[3];
    const float* ascale = (const float*)d_in[4];
    const int*   azp    = (const int*)d_in[5];
    const float* bias   = (const float*)d_in[6];
    float* out = (float*)d_out;

    const int N = in_sizes[2];          // OUT (weight_scales count)
    const int K = in_sizes[1] / N;      // IN
    const int M = in_sizes[0] / K;      // B*S

    // workspace carve-up (~48.1 MiB for 8192x4096 / 4096x4096)
    char* ws     = (char*)d_ws;
    char* xs     = ws;                                 // M*K int8
    char* wsq    = ws + (size_t)M * K;                 // N*K int8
    int*  rowsum = (int*)(wsq + (size_t)N * K);        // M int32
    float* alpha = (float*)((char*)rowsum + (size_t)M * 4);
    float* beta  = (float*)((char*)alpha + (size_t)N * 4);

    quant_rows<<<M, 256, 0, stream>>>(x, ascale, azp, xs, rowsum, K);

    long n4 = (long)N * K / 4;
    wconv<<<(int)((n4 + 255) / 256), 256, 0, stream>>>(
        (const int4*)wq, (char4*)wsq, n4);

    mkscales<<<(N + 255) / 256, 256, 0, stream>>>(wscale, wzp, ascale, alpha, beta, N);

    dim3 grid(N / BN, M / BM);
    gemm_i8<<<grid, 256, 0, stream>>>(xs, wsq, rowsum, alpha, beta, bias, out, M, N, K);
}

// Round 2
// 411.761 us; speedup vs baseline: 1.1617x; 1.1617x over previous
//
#include <hip/hip_runtime.h>
#include <hip/hip_bf16.h>

using int32x4 = __attribute__((ext_vector_type(4))) int;

#define BM 128
#define BN 128
#define BKQ 128  // K-bytes per staging step = 2 x mfma_i32_16x16x64_i8

// ---------------------------------------------------------------------------
// async 16B global->LDS (wave-uniform LDS base + lane*16)
__device__ __forceinline__ void load_lds16(const void* g, void* l) {
    __builtin_amdgcn_global_load_lds(
        (const __attribute__((address_space(1))) unsigned int*)g,
        (__attribute__((address_space(3))) unsigned int*)l, 16, 0, 0);
}

// ---------------------------------------------------------------------------
// Kernel 1: quantize activations to signed int8 (xq - a_zp) and per-row sums.
// Exact fp32 division + rintf matches numpy round-half-even.
__global__ __launch_bounds__(256) void quant_rows(
    const float* __restrict__ x, const float* __restrict__ act_scale,
    const int* __restrict__ act_zp, char* __restrict__ xs,
    int* __restrict__ rowsum, int K)
{
    __shared__ int wsum[4];
    const int row = blockIdx.x;
    const float s = act_scale[0];
    const int zp = act_zp[0];
    const float4* __restrict__ xr = (const float4*)(x + (size_t)row * K);
    char4* __restrict__ xo = (char4*)(xs + (size_t)row * K);
    const int nv = K >> 2;
    int sum = 0;
    for (int i = threadIdx.x; i < nv; i += 256) {
        float4 v = xr[i];
        int q0 = min(max((int)rintf(v.x / s) + zp, 0), 255) - zp;
        int q1 = min(max((int)rintf(v.y / s) + zp, 0), 255) - zp;
        int q2 = min(max((int)rintf(v.z / s) + zp, 0), 255) - zp;
        int q3 = min(max((int)rintf(v.w / s) + zp, 0), 255) - zp;
        sum += q0 + q1 + q2 + q3;
        char4 c;
        c.x = (char)q0; c.y = (char)q1; c.z = (char)q2; c.w = (char)q3;
        xo[i] = c;
    }
    for (int off = 32; off > 0; off >>= 1) sum += __shfl_down(sum, off, 64);
    if ((threadIdx.x & 63) == 0) wsum[threadIdx.x >> 6] = sum;
    __syncthreads();
    if (threadIdx.x == 0) rowsum[row] = wsum[0] + wsum[1] + wsum[2] + wsum[3];
}

// ---------------------------------------------------------------------------
// Kernel 2: weight int32 [N][K] -> int8 (w - 128)
__global__ __launch_bounds__(256) void wconv(
    const int4* __restrict__ wq, char4* __restrict__ wsq, long n4)
{
    long i = (long)blockIdx.x * 256 + threadIdx.x;
    if (i >= n4) return;
    int4 v = wq[i];
    char4 c;
    c.x = (char)(v.x - 128); c.y = (char)(v.y - 128);
    c.z = (char)(v.z - 128); c.w = (char)(v.w - 128);
    wsq[i] = c;
}

// ---------------------------------------------------------------------------
// Kernel 3: alpha[n] = a_s*w_s[n];  beta[n] = alpha[n]*(128-w_zp[n])
__global__ __launch_bounds__(256) void mkscales(
    const float* __restrict__ wscale, const int* __restrict__ wzp,
    const float* __restrict__ act_scale, float* __restrict__ alpha,
    float* __restrict__ beta, int N)
{
    int n = blockIdx.x * 256 + threadIdx.x;
    if (n >= N) return;
    float a = act_scale[0] * wscale[n];
    alpha[n] = a;
    beta[n] = a * (float)(128 - wzp[n]);
}

// ---------------------------------------------------------------------------
// Kernel 4: int8 GEMM. A=[M][K] i8, B=[N][K] i8. 128x128 tile, BK=128 bytes.
// 4 waves, each 64x64 via 4x4 grid of 16x16x64 MFMAs, 2 k-batches per stage.
//
// LDS swizzle (conflict-free ds_read_b128): physical 16B chunk (row, p)
// holds global k-chunk c = p ^ (row & 7). Staging lane->LDS is the fixed
// base+lane*16 mapping, so the swizzle is applied to the *global source*:
// lane fetches chunk c = (lane&7) ^ (lane>>3) of row (u*32 + wave*8 + lane>>3).
// Readers use p = c ^ (r&7) -> bank group (p mod 8) covers all 8 groups
// across 16 lanes (2 lanes each) => zero conflicts.
__global__ __launch_bounds__(256, 4) void gemm_i8(
    const char* __restrict__ Aq, const char* __restrict__ Bq,
    const int* __restrict__ rowsum, const float* __restrict__ alpha,
    const float* __restrict__ beta, const float* __restrict__ bias,
    float* __restrict__ C, int M, int N, int K)
{
    __shared__ __align__(16) char As[BM * BKQ];  // 16 KiB
    __shared__ __align__(16) char Bs[BN * BKQ];  // 16 KiB

    const int tid  = threadIdx.x;
    const int wave = tid >> 6;
    const int lane = tid & 63;

    const int n0 = blockIdx.x * BN;
    const int m0 = blockIdx.y * BM;

    const int wm = (wave & 1) * 64;   // wave's m-offset in tile
    const int wn = (wave >> 1) * 64;  // wave's n-offset in tile

    // --- staging source addresses (swizzled) ---
    const int srow = wave * 8 + (lane >> 3);            // row within 32-row band
    const int scol = ((lane & 7) ^ (lane >> 3)) * 16;   // swizzled k-chunk byte
    const char* ag = Aq + (size_t)(m0 + srow) * K + scol;
    const char* bg = Bq + (size_t)(n0 + srow) * K + scol;
    const size_t band = (size_t)32 * K;                 // 32-row band stride

    char* lA = As + wave * 1024;
    char* lB = Bs + wave * 1024;

    int32x4 acc[4][4] = {};

    const int r  = lane & 15;       // row within 16-tile (A: m, B: n)
    const int q  = lane >> 4;       // k quadrant (16B) within a k-batch
    const int rx = r & 7;           // swizzle key for reads

    for (int k0 = 0; k0 < K; k0 += BKQ) {
        __syncthreads();   // previous iteration's LDS reads done
#pragma unroll
        for (int u = 0; u < 4; u++) {
            load_lds16(ag + u * band, lA + u * 4096);
            load_lds16(bg + u * band, lB + u * 4096);
        }
        ag += BKQ;
        bg += BKQ;
        __syncthreads();   // staging drained

#pragma unroll
        for (int kb = 0; kb < 2; kb++) {
            int32x4 af[4], bf[4];
#pragma unroll
            for (int i = 0; i < 4; i++)
                af[i] = *(const int32x4*)(As + (wm + i * 16 + r) * 128
                                             + (((kb * 4 + q) ^ rx) * 16));
#pragma unroll
            for (int j = 0; j < 4; j++)
                bf[j] = *(const int32x4*)(Bs + (wn + j * 16 + r) * 128
                                             + (((kb * 4 + q) ^ rx) * 16));
#pragma unroll
            for (int i = 0; i < 4; i++)
#pragma unroll
                for (int j = 0; j < 4; j++)
                    acc[i][j] = __builtin_amdgcn_mfma_i32_16x16x64_i8(
                        af[i], bf[j], acc[i][j], 0, 0, 0);
        }
    }

    // epilogue: C/D layout col=lane&15, row=(lane>>4)*4+reg
    const int r4  = (lane >> 4) * 4;
    const int cil = lane & 15;
#pragma unroll
    for (int j = 0; j < 4; j++) {
        const int col = n0 + wn + j * 16 + cil;
        const float al = alpha[col];
        const float be = beta[col];
        const float bi = bias[col];
#pragma unroll
        for (int i = 0; i < 4; i++) {
            const int rowb = m0 + wm + i * 16 + r4;
#pragma unroll
            for (int t = 0; t < 4; t++) {
                const int row = rowb + t;
                C[(size_t)row * N + col] =
                    al * (float)acc[i][j][t] + be * (float)rowsum[row] + bi;
            }
        }
    }
}

// ---------------------------------------------------------------------------
extern "C" void kernel_launch(void* const* d_in, const int* in_sizes, int n_in,
                              void* d_out, int out_size, void* d_ws, size_t ws_size,
                              hipStream_t stream) {
    const float* x      = (const float*)d_in[0];
    const int*   wq     = (const int*)d_in[1];
    const float* wscale = (const float*)d_in[2];
    const int*   wzp    = (const int*)d_in[3];
    const float* ascale = (const float*)d_in[4];
    const int*   azp    = (const int*)d_in[5];
    const float* bias   = (const float*)d_in[6];
    float* out = (float*)d_out;

    const int N = in_sizes[2];          // OUT
    const int K = in_sizes[1] / N;      // IN
    const int M = in_sizes[0] / K;      // B*S

    char* ws     = (char*)d_ws;
    char* xs     = ws;                                 // M*K int8
    char* wsq    = ws + (size_t)M * K;                 // N*K int8
    int*  rowsum = (int*)(wsq + (size_t)N * K);        // M int32
    float* alpha = (float*)((char*)rowsum + (size_t)M * 4);
    float* beta  = (float*)((char*)alpha + (size_t)N * 4);

    quant_rows<<<M, 256, 0, stream>>>(x, ascale, azp, xs, rowsum, K);

    long n4 = (long)N * K / 4;
    wconv<<<(int)((n4 + 255) / 256), 256, 0, stream>>>(
        (const int4*)wq, (char4*)wsq, n4);

    mkscales<<<(N + 255) / 256, 256, 0, stream>>>(wscale, wzp, ascale, alpha, beta, N);

    dim3 grid(N / BN, M / BM);
    gemm_i8<<<grid, 256, 0, stream>>>(xs, wsq, rowsum, alpha, beta, bias, out, M, N, K);
}